// Round 1
// baseline (32572.461 us; speedup 1.0000x reference)
//
#include <hip/hip_runtime.h>
#include <hip/hip_cooperative_groups.h>
#include <math.h>

namespace cg = cooperative_groups;

// Problem constants
#define BZ   32
#define TENC 1500
#define DD   512      // E == H == A == ATT_H == 512
#define VV   10000
#define LL   100
#define SS   101      // L+1 steps
#define G4   2048     // 4*H
#define KCZ  1024     // H + A
#define NCHUNK 32     // attention t-chunks per batch row
#define CHSZ   47     // 32*47 = 1504 >= 1500

// d_out float offsets
#define OUT_LOGITS 0
#define OUT_ENCP   0                      // scratch overlay (dead before logits written)
#define OUT_PREG   24576000               // 32*1500*512
#define OUT_YSLP   32320000               // 32*101*10000
#define OUT_PRED   32323232
#define OUT_WS     32326464

__device__ inline float sigm(float x) { return 1.f / (1.f + __expf(-x)); }
__device__ inline float tanh_fast(float x) {
    x = fminf(15.f, fmaxf(-15.f, x));
    float e = __expf(2.f * x);
    return (e - 1.f) / (e + 1.f);
}

// ---------------------------------------------------------------------------
// Zero init: za slot 0 (32x1024) + c_state (32x512)
__global__ void zero_kernel(float* za0, float* cs) {
    int i = blockIdx.x * 256 + threadIdx.x;
    if (i < 32768) za0[i] = 0.f;
    else cs[i - 32768] = 0.f;
}

// ---------------------------------------------------------------------------
// Tiled fp32 GEMM, 128x128 tile, 8x8 per thread.
// MODE 0: enc_proj = enc_pad[48000x512] @ W_enc[512x512]         (B normal)
// MODE 1: pre_g = emb[tok][3232x512] @ W_ih[:, :512]^T + biases  (B transposed, A gathered)
// MODE 2: logits = za(+32 rows)[3232x1024] @ W_out^T + b_out     (B transposed, scattered out rows)
template<int MODE>
__global__ __launch_bounds__(256) void gemm_tile(
    const float* __restrict__ Abase, const float* __restrict__ Bmat,
    const float* __restrict__ bias0, const float* __restrict__ bias1,
    const int* __restrict__ ys, float* __restrict__ Out,
    int M, int N, int K)
{
    __shared__ float As[16][132];
    __shared__ float Bs[16][132];
    const int tid = threadIdx.x;
    const int row0 = blockIdx.y * 128, n0 = blockIdx.x * 128;

    const int ar = tid >> 1, ah = tid & 1;
    int am = row0 + ar; if (am > M - 1) am = M - 1;
    const float* Arow;
    if (MODE == 0) {
        Arow = Abase + (size_t)am * 512;
    } else if (MODE == 1) {
        int t = am >> 5, b = am & 31;
        int tok = (t == 0) ? 1 : ys[b * LL + t - 1];
        Arow = Abase + (size_t)tok * 512;
    } else {
        Arow = Abase + (size_t)(am + 32) * 1024;
    }
    const int bk = tid >> 4, bg = tid & 15;          // MODE 0
    const int bn = tid >> 1, bh = tid & 1;           // MODE 1/2
    int bnn = n0 + bn; if (bnn > N - 1) bnn = N - 1;

    const int tx = tid & 15, ty = tid >> 4;
    const int rr = ty * 8, cc = tx * 8;
    float acc[8][8] = {{0.f}};

    for (int k0 = 0; k0 < K; k0 += 16) {
        float4 a0 = *(const float4*)(Arow + k0 + ah * 8);
        float4 a1 = *(const float4*)(Arow + k0 + ah * 8 + 4);
        As[ah*8+0][ar] = a0.x; As[ah*8+1][ar] = a0.y; As[ah*8+2][ar] = a0.z; As[ah*8+3][ar] = a0.w;
        As[ah*8+4][ar] = a1.x; As[ah*8+5][ar] = a1.y; As[ah*8+6][ar] = a1.z; As[ah*8+7][ar] = a1.w;
        if (MODE == 0) {
            const float* bp = Bmat + (size_t)(k0 + bk) * N + n0 + bg * 8;
            float4 b0 = *(const float4*)(bp);
            float4 b1 = *(const float4*)(bp + 4);
            *(float4*)&Bs[bk][bg * 8]     = b0;
            *(float4*)&Bs[bk][bg * 8 + 4] = b1;
        } else {
            const float* bp = Bmat + (size_t)bnn * 1024 + k0 + bh * 8;
            float4 b0 = *(const float4*)(bp);
            float4 b1 = *(const float4*)(bp + 4);
            Bs[bh*8+0][bn] = b0.x; Bs[bh*8+1][bn] = b0.y; Bs[bh*8+2][bn] = b0.z; Bs[bh*8+3][bn] = b0.w;
            Bs[bh*8+4][bn] = b1.x; Bs[bh*8+5][bn] = b1.y; Bs[bh*8+6][bn] = b1.z; Bs[bh*8+7][bn] = b1.w;
        }
        __syncthreads();
        #pragma unroll
        for (int kk = 0; kk < 16; ++kk) {
            float4 A0 = *(const float4*)&As[kk][rr];
            float4 A1 = *(const float4*)&As[kk][rr + 4];
            float4 B0 = *(const float4*)&Bs[kk][cc];
            float4 B1 = *(const float4*)&Bs[kk][cc + 4];
            float av[8] = {A0.x, A0.y, A0.z, A0.w, A1.x, A1.y, A1.z, A1.w};
            float bv[8] = {B0.x, B0.y, B0.z, B0.w, B1.x, B1.y, B1.z, B1.w};
            #pragma unroll
            for (int i = 0; i < 8; ++i)
                #pragma unroll
                for (int j = 0; j < 8; ++j)
                    acc[i][j] += av[i] * bv[j];
        }
        __syncthreads();
    }
    #pragma unroll
    for (int i = 0; i < 8; ++i) {
        int m = row0 + rr + i;
        if (m >= M) continue;
        size_t orow;
        if (MODE == 2) { int t = m >> 5, b = m & 31; orow = ((size_t)b * SS + t) * (size_t)N; }
        else orow = (size_t)m * N;
        #pragma unroll
        for (int j = 0; j < 8; ++j) {
            int n = n0 + cc + j;
            if (n < N) {
                float v = acc[i][j];
                if (MODE == 1) v += bias0[n] + bias1[n];
                if (MODE == 2) v += bias0[n];
                Out[orow + n] = v;
            }
        }
    }
}

// ---------------------------------------------------------------------------
// Persistent cooperative decode loop: all 101 steps, 4 grid syncs per step.
// P1 gates+LSTM (512 block-items, K split in 2 halves via LDS)
// P2 qproj      (64 block-items)
// P3 attention partials (1024 block-items = 32 chunks x 32 batch)
// P4 finalize: reduce partials, normalize context, write w row (256 items)
__global__ __launch_bounds__(256, 4) void decode_loop(
    const float* __restrict__ enc_proj, const float* __restrict__ enc_pad,
    const int* __restrict__ enc_len,
    const float* __restrict__ W_ih, const float* __restrict__ W_hh,
    const float* __restrict__ W_dec, const float* __restrict__ v_att,
    const float* __restrict__ pre_g,
    float* __restrict__ za, float* __restrict__ c_state,
    float* __restrict__ q, float* __restrict__ p_buf,
    float* __restrict__ part_c, float* __restrict__ part_l,
    float* __restrict__ wsatt)
{
    cg::grid_group grid = cg::this_grid();
    const int tid = threadIdx.x;
    const int nb = gridDim.x;
    __shared__ float smem[3080];   // P1: [0,256)  P3: q_s[0,512) v_s[512,1024) accs[1024,3072) lsum[3072,3076)

    for (int t = 0; t < SS; ++t) {
        float* za_t = za + (size_t)t * (BZ * KCZ);
        float* za_n = za_t + BZ * KCZ;
        const float* pg_t = pre_g + (size_t)t * (BZ * G4);

        // ---- P1: gates + LSTM. item = h in [0,512) ----
        for (int h = blockIdx.x; h < 512; h += nb) {
            const int b = tid & 31, gl = (tid >> 5) & 3, kh = tid >> 7;
            const int r = gl * 512 + h;
            const float* src = za_t + b * KCZ + kh * 512;   // z half | c half
            const float* wm = kh ? (W_ih + (size_t)r * 1024 + 512)
                                 : (W_hh + (size_t)r * 512);
            float acc = 0.f;
            #pragma unroll 8
            for (int k = 0; k < 512; k += 4) {
                float4 s4 = *(const float4*)(src + k);
                float4 w4 = *(const float4*)(wm + k);
                acc += s4.x*w4.x + s4.y*w4.y + s4.z*w4.z + s4.w*w4.w;
            }
            smem[kh * 128 + gl * 32 + b] = acc;
            __syncthreads();
            if (tid < 32) {
                const int bb = tid;
                const float* pg = pg_t + bb * G4 + h;
                float vi = smem[  0 + bb] + smem[128 +   0 + bb] + pg[0];
                float vf = smem[ 32 + bb] + smem[128 +  32 + bb] + pg[512];
                float vg = smem[ 64 + bb] + smem[128 +  64 + bb] + pg[1024];
                float vo = smem[ 96 + bb] + smem[128 +  96 + bb] + pg[1536];
                float ig = sigm(vi), fg = sigm(vf), gg = tanhf(vg), og = sigm(vo);
                float c = fg * c_state[bb * 512 + h] + ig * gg;
                c_state[bb * 512 + h] = c;
                za_n[bb * KCZ + h] = og * tanhf(c);
            }
            __syncthreads();
        }
        grid.sync();

        // ---- P2: q = z_new @ W_dec. item in [0,64) ----
        for (int it = blockIdx.x; it < 64; it += nb) {
            const int j = (it & 15) * 32 + (tid & 31);
            const int b = (it >> 4) * 8 + (tid >> 5);
            const float* z = za_n + b * KCZ;
            float acc = 0.f;
            #pragma unroll 4
            for (int h = 0; h < 512; h += 4) {
                float4 z4 = *(const float4*)(z + h);
                acc += z4.x * W_dec[(h + 0) * 512 + j];
                acc += z4.y * W_dec[(h + 1) * 512 + j];
                acc += z4.z * W_dec[(h + 2) * 512 + j];
                acc += z4.w * W_dec[(h + 3) * 512 + j];
            }
            q[b * 512 + j] = acc;
        }
        grid.sync();

        // ---- P3: attention partials. item in [0,1024): b = it&31, tc = it>>5 ----
        for (int it = blockIdx.x; it < NCHUNK * BZ; it += nb) {
            const int b = it & 31, tc = it >> 5;
            const int len = enc_len[b];
            const int base = tc * CHSZ;
            int lim = base + CHSZ;
            if (lim > TENC) lim = TENC;
            if (lim > len) lim = len;
            if (base >= lim) continue;   // block-uniform

            float* smq = smem;
            float* smv = smem + 512;
            float* acs = smem + 1024;
            for (int i = tid; i < 512; i += 256) { smq[i] = q[b * 512 + i]; smv[i] = v_att[i]; }
            __syncthreads();
            const int wave = tid >> 6, lane = tid & 63;
            float a[8] = {0.f, 0.f, 0.f, 0.f, 0.f, 0.f, 0.f, 0.f};
            float lacc = 0.f;
            float qv[8], vv8[8];
            #pragma unroll
            for (int j = 0; j < 8; ++j) { qv[j] = smq[lane * 8 + j]; vv8[j] = smv[lane * 8 + j]; }

            for (int tp = base + wave; tp < lim; tp += 4) {
                const float* ep = enc_proj + ((size_t)b * TENC + tp) * 512 + lane * 8;
                float4 e0 = *(const float4*)(ep);
                float4 e1 = *(const float4*)(ep + 4);
                float s = tanh_fast(e0.x + qv[0]) * vv8[0] + tanh_fast(e0.y + qv[1]) * vv8[1]
                        + tanh_fast(e0.z + qv[2]) * vv8[2] + tanh_fast(e0.w + qv[3]) * vv8[3]
                        + tanh_fast(e1.x + qv[4]) * vv8[4] + tanh_fast(e1.y + qv[5]) * vv8[5]
                        + tanh_fast(e1.z + qv[6]) * vv8[6] + tanh_fast(e1.w + qv[7]) * vv8[7];
                #pragma unroll
                for (int off = 32; off > 0; off >>= 1) s += __shfl_xor(s, off);
                float p = __expf(s - 10.f);
                if (lane == 0) p_buf[b * TENC + tp] = p;
                lacc += p;
                const float* xp = enc_pad + ((size_t)b * TENC + tp) * 512 + lane * 8;
                float4 x0 = *(const float4*)(xp);
                float4 x1 = *(const float4*)(xp + 4);
                a[0] += p * x0.x; a[1] += p * x0.y; a[2] += p * x0.z; a[3] += p * x0.w;
                a[4] += p * x1.x; a[5] += p * x1.y; a[6] += p * x1.z; a[7] += p * x1.w;
            }
            #pragma unroll
            for (int j = 0; j < 8; ++j) acs[wave * 512 + lane * 8 + j] = a[j];
            if (lane == 0) smem[3072 + wave] = lacc;
            __syncthreads();
            for (int d = tid; d < 512; d += 256)
                part_c[(size_t)it * 512 + d] = acs[d] + acs[512 + d] + acs[1024 + d] + acs[1536 + d];
            if (tid == 0) part_l[it] = smem[3072] + smem[3073] + smem[3074] + smem[3075];
            __syncthreads();
        }
        grid.sync();

        // ---- P4: finalize. item in [0,256): b = it>>3, seg = it&7 ----
        for (int it = blockIdx.x; it < 256; it += nb) {
            const int b = it >> 3, seg = it & 7;
            const int len = enc_len[b];
            const int nch = (len + CHSZ - 1) / CHSZ;
            float l = 0.f;
            for (int tc = 0; tc < nch; ++tc) l += part_l[(tc << 5) | b];
            const float linv = 1.f / l;
            if (tid < 64) {
                const int d = seg * 64 + tid;
                float s = 0.f;
                for (int tc = 0; tc < nch; ++tc)
                    s += part_c[((size_t)((tc << 5) | b)) * 512 + d];
                za_n[b * KCZ + 512 + d] = s * linv;
            }
            float* wrow = wsatt + (size_t)b * (SS * TENC) + (size_t)t * TENC;
            const int tp0 = seg * 188;
            int tp1 = tp0 + 188; if (tp1 > TENC) tp1 = TENC;
            for (int tp = tp0 + tid; tp < tp1; tp += 256)
                wrow[tp] = (tp < len) ? p_buf[b * TENC + tp] * linv : 0.f;
        }
        grid.sync();
    }
}

// ---------------------------------------------------------------------------
// Per-row log-softmax stats: max, argmax(first), logsumexp -> ys_lp, pred
__global__ __launch_bounds__(256) void k_logsm(const float* __restrict__ logits,
                                               const int* __restrict__ ys,
                                               float* __restrict__ ys_lp,
                                               float* __restrict__ pred)
{
    __shared__ float sval[256];
    __shared__ int   sidx[256];
    __shared__ float ssum[256];
    const int bid = blockIdx.x, tid = threadIdx.x;
    const float* row = logits + (size_t)bid * VV;
    float vmax = -3.4e38f; int imax = 0;
    for (int v4 = tid; v4 < VV / 4; v4 += 256) {
        float4 x = *(const float4*)(row + v4 * 4);
        int basei = v4 * 4;
        if (x.x > vmax) { vmax = x.x; imax = basei; }
        if (x.y > vmax) { vmax = x.y; imax = basei + 1; }
        if (x.z > vmax) { vmax = x.z; imax = basei + 2; }
        if (x.w > vmax) { vmax = x.w; imax = basei + 3; }
    }
    sval[tid] = vmax; sidx[tid] = imax;
    __syncthreads();
    for (int s = 128; s > 0; s >>= 1) {
        if (tid < s) {
            float v2 = sval[tid + s]; int i2 = sidx[tid + s];
            if (v2 > sval[tid] || (v2 == sval[tid] && i2 < sidx[tid])) { sval[tid] = v2; sidx[tid] = i2; }
        }
        __syncthreads();
    }
    const float gmax = sval[0];
    float lsum = 0.f;
    for (int v4 = tid; v4 < VV / 4; v4 += 256) {
        float4 x = *(const float4*)(row + v4 * 4);
        lsum += __expf(x.x - gmax) + __expf(x.y - gmax) + __expf(x.z - gmax) + __expf(x.w - gmax);
    }
    ssum[tid] = lsum;
    __syncthreads();
    for (int s = 128; s > 0; s >>= 1) {
        if (tid < s) ssum[tid] += ssum[tid + s];
        __syncthreads();
    }
    if (tid == 0) {
        int b = bid / SS, t = bid % SS;
        int tok = (t < LL) ? ys[b * LL + t] : 2;   // EOS = 2
        ys_lp[bid] = row[tok] - gmax - logf(ssum[0]);
        pred[bid]  = (float)sidx[0];
    }
}

// ---------------------------------------------------------------------------
extern "C" void kernel_launch(void* const* d_in, const int* in_sizes, int n_in,
                              void* d_out, int out_size, void* d_ws, size_t ws_size,
                              hipStream_t stream)
{
    const float* enc_pad = (const float*)d_in[0];
    const int*   enc_len = (const int*)d_in[1];
    const int*   ys      = (const int*)d_in[2];
    const float* emb     = (const float*)d_in[3];
    const float* W_ih    = (const float*)d_in[4];
    const float* W_hh    = (const float*)d_in[5];
    const float* b_ih    = (const float*)d_in[6];
    const float* b_hh    = (const float*)d_in[7];
    const float* W_enc   = (const float*)d_in[8];
    const float* W_dec   = (const float*)d_in[9];
    const float* v_att   = (const float*)d_in[10];
    const float* W_out   = (const float*)d_in[11];
    const float* b_out   = (const float*)d_in[12];

    float* out = (float*)d_out;
    float* enc_proj = out + OUT_ENCP;
    float* pre_g    = out + OUT_PREG;
    float* logits   = out + OUT_LOGITS;
    float* ys_lp    = out + OUT_YSLP;
    float* predo    = out + OUT_PRED;
    float* wsatt    = out + OUT_WS;

    float* ws = (float*)d_ws;
    float* za      = ws;                    // 102*32*1024 = 3342336
    float* c_state = za + 3342336;          // 16384
    float* qbuf    = c_state + 16384;       // 16384
    float* p_buf   = qbuf + 16384;          // 48000
    float* part_c  = p_buf + 48000;         // 1024*512 = 524288
    float* part_l  = part_c + 524288;       // 1024

    // Prologue
    zero_kernel<<<192, 256, 0, stream>>>(za, c_state);
    gemm_tile<0><<<dim3(4, 375), 256, 0, stream>>>(enc_pad, W_enc, nullptr, nullptr, nullptr,
                                                   enc_proj, BZ * TENC, 512, 512);
    gemm_tile<1><<<dim3(16, 26), 256, 0, stream>>>(emb, W_ih, b_ih, b_hh, ys,
                                                   pre_g, BZ * SS, G4, 512);

    // Persistent cooperative decode loop
    static int coop_grid = 0;
    if (coop_grid == 0) {
        int occ = 0;
        hipOccupancyMaxActiveBlocksPerMultiprocessor(&occ, decode_loop, 256, 0);
        if (occ < 1) occ = 1;
        if (occ > 4) occ = 4;               // 1024 block-items max useful
        coop_grid = occ * 256;              // 256 CUs on MI355X
        if (coop_grid > 1024) coop_grid = 1024;
    }
    void* cargs[] = {
        (void*)&enc_proj, (void*)&enc_pad, (void*)&enc_len,
        (void*)&W_ih, (void*)&W_hh, (void*)&W_dec, (void*)&v_att,
        (void*)&pre_g, (void*)&za, (void*)&c_state, (void*)&qbuf,
        (void*)&p_buf, (void*)&part_c, (void*)&part_l, (void*)&wsatt
    };
    hipLaunchCooperativeKernel(decode_loop, dim3(coop_grid), dim3(256), cargs, 0, stream);

    // Epilogue
    gemm_tile<2><<<dim3(79, 26), 256, 0, stream>>>(za, W_out, b_out, nullptr, nullptr,
                                                   logits, BZ * SS, VV, 1024);
    k_logsm<<<BZ * SS, 256, 0, stream>>>(logits, ys, ys_lp, predo);
}

// Round 2
// 8839.285 us; speedup vs baseline: 3.6850x; 3.6850x over previous
//
#include <hip/hip_runtime.h>
#include <math.h>

// Problem constants
#define BZ   32
#define TENC 1500
#define DD   512      // E == H == A == ATT_H == 512
#define VV   10000
#define LL   100
#define SS   101      // L+1 steps
#define G4   2048     // 4*H
#define KCZ  1024     // H + A
#define ACH  32       // attention t-chunk size
#define NCH  47       // ceil(1500/32)

// d_out float offsets
#define OUT_LOGITS 0
#define OUT_ENCP   0                      // scratch overlay (dead before logits written)
#define OUT_PREG   24576000               // 32*1500*512
#define OUT_YSLP   32320000               // 32*101*10000
#define OUT_PRED   32323232
#define OUT_WS     32326464

// ws float offsets
#define WS_ZA      0                      // 102*32*1024 = 3342336
#define WS_CST     3342336                // 32*512 = 16384
#define WS_LALL    3358720                // 101*32 = 3232 (padded region zeroed)
#define WS_Q       3361952                // 32*512
#define WS_ZERON   3361952                // floats zeroed at prologue

__device__ inline float sigm(float x) { return 1.f / (1.f + __expf(-x)); }
__device__ inline float tanh_fast(float x) {
    x = fminf(15.f, fmaxf(-15.f, x));
    float e = __expf(2.f * x);
    return (e - 1.f) / (e + 1.f);
}

// ---------------------------------------------------------------------------
// Zero init: za (all slots, z+c halves) + c_state + l_all, contiguous in ws
__global__ void zero_kernel(float* ws) {
    size_t i = (size_t)blockIdx.x * 256 + threadIdx.x;
    if (i < WS_ZERON) ws[i] = 0.f;
}

// ---------------------------------------------------------------------------
// Tiled fp32 GEMM, 128x128 tile, 8x8 per thread.
// MODE 0: enc_proj = enc_pad[48000x512] @ W_enc[512x512]         (B normal)
// MODE 1: pre_g = emb[tok][3232x512] @ W_ih[:, :512]^T + biases  (B transposed, A gathered)
// MODE 2: logits = za(+32 rows)[3232x1024] @ W_out^T + b_out     (B transposed, scattered out
//         rows, c-columns [512:1024) scaled by 1/l_all[row])
template<int MODE>
__global__ __launch_bounds__(256) void gemm_tile(
    const float* __restrict__ Abase, const float* __restrict__ Bmat,
    const float* __restrict__ bias0, const float* __restrict__ bias1,
    const int* __restrict__ ys, const float* __restrict__ l_all,
    float* __restrict__ Out, int M, int N, int K)
{
    __shared__ float As[16][132];
    __shared__ float Bs[16][132];
    const int tid = threadIdx.x;
    const int row0 = blockIdx.y * 128, n0 = blockIdx.x * 128;

    const int ar = tid >> 1, ah = tid & 1;
    int am = row0 + ar; if (am > M - 1) am = M - 1;
    const float* Arow;
    float linvA = 1.f;
    if (MODE == 0) {
        Arow = Abase + (size_t)am * 512;
    } else if (MODE == 1) {
        int t = am >> 5, b = am & 31;
        int tok = (t == 0) ? 1 : ys[b * LL + t - 1];
        Arow = Abase + (size_t)tok * 512;
    } else {
        Arow = Abase + (size_t)(am + 32) * 1024;
        linvA = 1.f / l_all[am];           // l_all laid out [t][b] == row index
    }
    const int bk = tid >> 4, bg = tid & 15;          // MODE 0
    const int bn = tid >> 1, bh = tid & 1;           // MODE 1/2
    int bnn = n0 + bn; if (bnn > N - 1) bnn = N - 1;

    const int tx = tid & 15, ty = tid >> 4;
    const int rr = ty * 8, cc = tx * 8;
    float acc[8][8] = {{0.f}};

    for (int k0 = 0; k0 < K; k0 += 16) {
        float4 a0 = *(const float4*)(Arow + k0 + ah * 8);
        float4 a1 = *(const float4*)(Arow + k0 + ah * 8 + 4);
        if (MODE == 2) {
            float sc = (k0 + ah * 8 >= 512) ? linvA : 1.f;
            a0.x *= sc; a0.y *= sc; a0.z *= sc; a0.w *= sc;
            a1.x *= sc; a1.y *= sc; a1.z *= sc; a1.w *= sc;
        }
        As[ah*8+0][ar] = a0.x; As[ah*8+1][ar] = a0.y; As[ah*8+2][ar] = a0.z; As[ah*8+3][ar] = a0.w;
        As[ah*8+4][ar] = a1.x; As[ah*8+5][ar] = a1.y; As[ah*8+6][ar] = a1.z; As[ah*8+7][ar] = a1.w;
        if (MODE == 0) {
            const float* bp = Bmat + (size_t)(k0 + bk) * N + n0 + bg * 8;
            float4 b0 = *(const float4*)(bp);
            float4 b1 = *(const float4*)(bp + 4);
            *(float4*)&Bs[bk][bg * 8]     = b0;
            *(float4*)&Bs[bk][bg * 8 + 4] = b1;
        } else {
            const float* bp = Bmat + (size_t)bnn * 1024 + k0 + bh * 8;
            float4 b0 = *(const float4*)(bp);
            float4 b1 = *(const float4*)(bp + 4);
            Bs[bh*8+0][bn] = b0.x; Bs[bh*8+1][bn] = b0.y; Bs[bh*8+2][bn] = b0.z; Bs[bh*8+3][bn] = b0.w;
            Bs[bh*8+4][bn] = b1.x; Bs[bh*8+5][bn] = b1.y; Bs[bh*8+6][bn] = b1.z; Bs[bh*8+7][bn] = b1.w;
        }
        __syncthreads();
        #pragma unroll
        for (int kk = 0; kk < 16; ++kk) {
            float4 A0 = *(const float4*)&As[kk][rr];
            float4 A1 = *(const float4*)&As[kk][rr + 4];
            float4 B0 = *(const float4*)&Bs[kk][cc];
            float4 B1 = *(const float4*)&Bs[kk][cc + 4];
            float av[8] = {A0.x, A0.y, A0.z, A0.w, A1.x, A1.y, A1.z, A1.w};
            float bv[8] = {B0.x, B0.y, B0.z, B0.w, B1.x, B1.y, B1.z, B1.w};
            #pragma unroll
            for (int i = 0; i < 8; ++i)
                #pragma unroll
                for (int j = 0; j < 8; ++j)
                    acc[i][j] += av[i] * bv[j];
        }
        __syncthreads();
    }
    #pragma unroll
    for (int i = 0; i < 8; ++i) {
        int m = row0 + rr + i;
        if (m >= M) continue;
        size_t orow;
        if (MODE == 2) { int t = m >> 5, b = m & 31; orow = ((size_t)b * SS + t) * (size_t)N; }
        else orow = (size_t)m * N;
        #pragma unroll
        for (int j = 0; j < 8; ++j) {
            int n = n0 + cc + j;
            if (n < N) {
                float v = acc[i][j];
                if (MODE == 1) v += bias0[n] + bias1[n];
                if (MODE == 2) v += bias0[n];
                Out[orow + n] = v;
            }
        }
    }
}

// ---------------------------------------------------------------------------
// Fused gates + LSTM. One block per h in [0,512).
// thread = (b 0..31, gate 0..3, k-half 0..1); k-half 1 (context) is scaled by 1/l.
__global__ __launch_bounds__(256) void k_glstm(
    const float* __restrict__ za_t, const float* __restrict__ pre_g_t,
    const float* __restrict__ W_ih, const float* __restrict__ W_hh,
    const float* __restrict__ l_all, int t,
    float* __restrict__ c_state, float* __restrict__ za_n)
{
    __shared__ float red[256];
    const int h = blockIdx.x, tid = threadIdx.x;
    const int b = tid & 31, gl = (tid >> 5) & 3, kh = tid >> 7;
    const int r = gl * 512 + h;
    const float* src = za_t + b * KCZ + kh * 512;     // z half | raw-c half
    const float* wm = kh ? (W_ih + (size_t)r * 1024 + 512)
                         : (W_hh + (size_t)r * 512);
    float acc = 0.f;
    #pragma unroll 8
    for (int k = 0; k < 512; k += 4) {
        float4 s4 = *(const float4*)(src + k);
        float4 w4 = *(const float4*)(wm + k);
        acc += s4.x*w4.x + s4.y*w4.y + s4.z*w4.z + s4.w*w4.w;
    }
    if (kh) {
        float linv = (t == 0) ? 0.f : 1.f / l_all[(t - 1) * 32 + b];
        acc *= linv;
    }
    red[kh * 128 + gl * 32 + b] = acc;
    __syncthreads();
    if (tid < 32) {
        const int bb = tid;
        const float* pg = pre_g_t + bb * G4 + h;
        float vi = red[  0 + bb] + red[128 +   0 + bb] + pg[0];
        float vf = red[ 32 + bb] + red[128 +  32 + bb] + pg[512];
        float vg = red[ 64 + bb] + red[128 +  64 + bb] + pg[1024];
        float vo = red[ 96 + bb] + red[128 +  96 + bb] + pg[1536];
        float ig = sigm(vi), fg = sigm(vf), gg = tanhf(vg), og = sigm(vo);
        float c = fg * c_state[bb * 512 + h] + ig * gg;
        c_state[bb * 512 + h] = c;
        za_n[bb * KCZ + h] = og * tanhf(c);
    }
}

// ---------------------------------------------------------------------------
// q = z_new @ W_dec, split-K. grid (16 jc, 32 b); thread = (j-lane 0..31, kseg 0..7)
__global__ __launch_bounds__(256) void k_qproj(const float* __restrict__ za_n,
                                               const float* __restrict__ W_dec,
                                               float* __restrict__ q)
{
    __shared__ float red[256];
    const int tid = threadIdx.x;
    const int j = blockIdx.x * 32 + (tid & 31);
    const int b = blockIdx.y;
    const int k0 = (tid >> 5) * 64;
    const float* z = za_n + b * KCZ + k0;
    const float* wd = W_dec + (size_t)k0 * 512 + j;
    float acc = 0.f;
    #pragma unroll 8
    for (int k = 0; k < 64; k += 4) {
        float4 z4 = *(const float4*)(z + k);
        acc += z4.x * wd[(k + 0) * 512] + z4.y * wd[(k + 1) * 512]
             + z4.z * wd[(k + 2) * 512] + z4.w * wd[(k + 3) * 512];
    }
    red[tid] = acc;
    __syncthreads();
    if (tid < 32) {
        float s = red[tid] + red[tid + 32] + red[tid + 64] + red[tid + 96]
                + red[tid + 128] + red[tid + 160] + red[tid + 192] + red[tid + 224];
        q[b * 512 + blockIdx.x * 32 + tid] = s;
    }
}

// ---------------------------------------------------------------------------
// Fused attention: e -> p=exp(e-10) -> raw p to ws row, unnormalized context
// accumulated into za_next c-half, l into l_all[t][b].
// grid (47 t-chunks, 32 b), 256 threads = 4 waves; wave handles one t' at a time.
__global__ __launch_bounds__(256) void k_att(
    const float* __restrict__ enc_proj, const float* __restrict__ enc_pad,
    const float* __restrict__ q, const float* __restrict__ v_att,
    const int* __restrict__ enc_len,
    float* __restrict__ za_n, float* __restrict__ l_t, float* __restrict__ w_raw)
{
    __shared__ float q_s[512], v_s[512];
    __shared__ float accs[4][512];
    __shared__ float lsum_s[4];
    const int b = blockIdx.y, tc = blockIdx.x, tid = threadIdx.x;
    int len = enc_len[b]; if (len > TENC) len = TENC;
    const int base = tc * ACH;
    int tlim = base + ACH;
    if (tlim > len) tlim = len;
    if (base >= tlim) return;                 // block-uniform, before any sync

    for (int i = tid; i < 512; i += 256) { q_s[i] = q[b * 512 + i]; v_s[i] = v_att[i]; }
    __syncthreads();
    const int wave = tid >> 6, lane = tid & 63;
    float a[8] = {0.f, 0.f, 0.f, 0.f, 0.f, 0.f, 0.f, 0.f};
    float lacc = 0.f;
    float qv[8], vv8[8];
    #pragma unroll
    for (int j = 0; j < 8; ++j) { qv[j] = q_s[lane * 8 + j]; vv8[j] = v_s[lane * 8 + j]; }

    for (int tp = base + wave; tp < tlim; tp += 4) {
        const float* ep = enc_proj + ((size_t)b * TENC + tp) * 512 + lane * 8;
        float4 e0 = *(const float4*)(ep);
        float4 e1 = *(const float4*)(ep + 4);
        float s = tanh_fast(e0.x + qv[0]) * vv8[0] + tanh_fast(e0.y + qv[1]) * vv8[1]
                + tanh_fast(e0.z + qv[2]) * vv8[2] + tanh_fast(e0.w + qv[3]) * vv8[3]
                + tanh_fast(e1.x + qv[4]) * vv8[4] + tanh_fast(e1.y + qv[5]) * vv8[5]
                + tanh_fast(e1.z + qv[6]) * vv8[6] + tanh_fast(e1.w + qv[7]) * vv8[7];
        #pragma unroll
        for (int off = 32; off > 0; off >>= 1) s += __shfl_xor(s, off);
        float p = __expf(s - 10.f);
        if (lane == 0) w_raw[(size_t)b * (SS * TENC) + tp] = p;
        lacc += p;
        const float* xp = enc_pad + ((size_t)b * TENC + tp) * 512 + lane * 8;
        float4 x0 = *(const float4*)(xp);
        float4 x1 = *(const float4*)(xp + 4);
        a[0] += p * x0.x; a[1] += p * x0.y; a[2] += p * x0.z; a[3] += p * x0.w;
        a[4] += p * x1.x; a[5] += p * x1.y; a[6] += p * x1.z; a[7] += p * x1.w;
    }
    #pragma unroll
    for (int j = 0; j < 8; ++j) accs[wave][lane * 8 + j] = a[j];
    if (lane == 0) lsum_s[wave] = lacc;
    __syncthreads();
    for (int d = tid; d < 512; d += 256) {
        float s = accs[0][d] + accs[1][d] + accs[2][d] + accs[3][d];
        atomicAdd(&za_n[b * KCZ + 512 + d], s);
    }
    if (tid == 0) atomicAdd(&l_t[b], lsum_s[0] + lsum_s[1] + lsum_s[2] + lsum_s[3]);
}

// ---------------------------------------------------------------------------
// Normalize all attention-weight rows in one pass. grid 3232 = B*SS rows.
__global__ __launch_bounds__(256) void k_wnorm(float* __restrict__ wsatt,
                                               const float* __restrict__ l_all,
                                               const int* __restrict__ enc_len)
{
    const int rid = blockIdx.x;               // b*SS + t
    const int b = rid / SS, t = rid % SS;
    const float linv = 1.f / l_all[t * 32 + b];
    const int len = enc_len[b];
    float* row = wsatt + (size_t)rid * TENC;
    for (int tp = threadIdx.x; tp < TENC; tp += 256)
        row[tp] = (tp < len) ? row[tp] * linv : 0.f;
}

// ---------------------------------------------------------------------------
// Per-row log-softmax stats: max, argmax(first), logsumexp -> ys_lp, pred
__global__ __launch_bounds__(256) void k_logsm(const float* __restrict__ logits,
                                               const int* __restrict__ ys,
                                               float* __restrict__ ys_lp,
                                               float* __restrict__ pred)
{
    __shared__ float sval[256];
    __shared__ int   sidx[256];
    __shared__ float ssum[256];
    const int bid = blockIdx.x, tid = threadIdx.x;
    const float* row = logits + (size_t)bid * VV;
    float vmax = -3.4e38f; int imax = 0;
    for (int v4 = tid; v4 < VV / 4; v4 += 256) {
        float4 x = *(const float4*)(row + v4 * 4);
        int basei = v4 * 4;
        if (x.x > vmax) { vmax = x.x; imax = basei; }
        if (x.y > vmax) { vmax = x.y; imax = basei + 1; }
        if (x.z > vmax) { vmax = x.z; imax = basei + 2; }
        if (x.w > vmax) { vmax = x.w; imax = basei + 3; }
    }
    sval[tid] = vmax; sidx[tid] = imax;
    __syncthreads();
    for (int s = 128; s > 0; s >>= 1) {
        if (tid < s) {
            float v2 = sval[tid + s]; int i2 = sidx[tid + s];
            if (v2 > sval[tid] || (v2 == sval[tid] && i2 < sidx[tid])) { sval[tid] = v2; sidx[tid] = i2; }
        }
        __syncthreads();
    }
    const float gmax = sval[0];
    float lsum = 0.f;
    for (int v4 = tid; v4 < VV / 4; v4 += 256) {
        float4 x = *(const float4*)(row + v4 * 4);
        lsum += __expf(x.x - gmax) + __expf(x.y - gmax) + __expf(x.z - gmax) + __expf(x.w - gmax);
    }
    ssum[tid] = lsum;
    __syncthreads();
    for (int s = 128; s > 0; s >>= 1) {
        if (tid < s) ssum[tid] += ssum[tid + s];
        __syncthreads();
    }
    if (tid == 0) {
        int b = bid / SS, t = bid % SS;
        int tok = (t < LL) ? ys[b * LL + t] : 2;   // EOS = 2
        ys_lp[bid] = row[tok] - gmax - logf(ssum[0]);
        pred[bid]  = (float)sidx[0];
    }
}

// ---------------------------------------------------------------------------
extern "C" void kernel_launch(void* const* d_in, const int* in_sizes, int n_in,
                              void* d_out, int out_size, void* d_ws, size_t ws_size,
                              hipStream_t stream)
{
    const float* enc_pad = (const float*)d_in[0];
    const int*   enc_len = (const int*)d_in[1];
    const int*   ys      = (const int*)d_in[2];
    const float* emb     = (const float*)d_in[3];
    const float* W_ih    = (const float*)d_in[4];
    const float* W_hh    = (const float*)d_in[5];
    const float* b_ih    = (const float*)d_in[6];
    const float* b_hh    = (const float*)d_in[7];
    const float* W_enc   = (const float*)d_in[8];
    const float* W_dec   = (const float*)d_in[9];
    const float* v_att   = (const float*)d_in[10];
    const float* W_out   = (const float*)d_in[11];
    const float* b_out   = (const float*)d_in[12];

    float* out = (float*)d_out;
    float* enc_proj = out + OUT_ENCP;
    float* pre_g    = out + OUT_PREG;
    float* logits   = out + OUT_LOGITS;
    float* ys_lp    = out + OUT_YSLP;
    float* predo    = out + OUT_PRED;
    float* wsatt    = out + OUT_WS;

    float* ws = (float*)d_ws;
    float* za      = ws + WS_ZA;            // 102*32*1024
    float* c_state = ws + WS_CST;           // 32*512
    float* l_all   = ws + WS_LALL;          // 101*32
    float* qbuf    = ws + WS_Q;             // 32*512

    // Prologue
    zero_kernel<<<(WS_ZERON + 255) / 256, 256, 0, stream>>>(ws);
    gemm_tile<0><<<dim3(4, 375), 256, 0, stream>>>(enc_pad, W_enc, nullptr, nullptr, nullptr,
                                                   nullptr, enc_proj, BZ * TENC, 512, 512);
    gemm_tile<1><<<dim3(16, 26), 256, 0, stream>>>(emb, W_ih, b_ih, b_hh, ys,
                                                   nullptr, pre_g, BZ * SS, G4, 512);

    // Sequential decode: 3 kernels per step
    for (int t = 0; t < SS; ++t) {
        float* za_t    = za + (size_t)t * (BZ * KCZ);
        float* za_next = za_t + BZ * KCZ;
        k_glstm<<<512, 256, 0, stream>>>(za_t, pre_g + (size_t)t * (BZ * G4),
                                         W_ih, W_hh, l_all, t, c_state, za_next);
        k_qproj<<<dim3(16, 32), 256, 0, stream>>>(za_next, W_dec, qbuf);
        k_att<<<dim3(NCH, 32), 256, 0, stream>>>(enc_proj, enc_pad, qbuf, v_att, enc_len,
                                                 za_next, l_all + t * 32,
                                                 wsatt + (size_t)t * TENC);
    }

    // Epilogue
    k_wnorm<<<BZ * SS, 256, 0, stream>>>(wsatt, l_all, enc_len);
    gemm_tile<2><<<dim3(79, 26), 256, 0, stream>>>(za, W_out, b_out, nullptr, nullptr,
                                                   l_all, logits, BZ * SS, VV, 1024);
    k_logsm<<<BZ * SS, 256, 0, stream>>>(logits, ys, ys_lp, predo);
}

// Round 3
// 6260.886 us; speedup vs baseline: 5.2025x; 1.4118x over previous
//
#include <hip/hip_runtime.h>
#include <math.h>

// Problem constants
#define BZ   32
#define TENC 1500
#define DD   512      // E == H == A == ATT_H == 512
#define VV   10000
#define LL   100
#define SS   101      // L+1 steps
#define G4   2048     // 4*H
#define KCZ  1024     // H + A
#define ACH  32       // attention t-chunk size
#define NCH  47       // ceil(1500/32)

// d_out float offsets
#define OUT_LOGITS 0
#define OUT_ENCP   0                      // scratch overlay (dead before logits written)
#define OUT_PREG   24576000               // 32*1500*512
#define OUT_YSLP   32320000               // 32*101*10000
#define OUT_PRED   32323232
#define OUT_WS     32326464

// ws float offsets
#define WS_ZA      0                      // 102*32*1024 = 3342336
#define WS_CST     3342336                // 32*512 = 16384
#define WS_LALL    3358720                // 101*32 = 3232
#define WS_Q       3361952                // 32*512
#define WS_ZERON   3361952                // floats zeroed at prologue

__device__ inline float sigm(float x) { return 1.f / (1.f + __expf(-x)); }
__device__ inline float tanh_fast(float x) {
    x = fminf(15.f, fmaxf(-15.f, x));
    float e = __expf(2.f * x);
    return (e - 1.f) / (e + 1.f);
}

// ---------------------------------------------------------------------------
// Zero init: za (all slots) + c_state + l_all, contiguous in ws
__global__ void zero_kernel(float* ws) {
    size_t i = (size_t)blockIdx.x * 256 + threadIdx.x;
    if (i < WS_ZERON) ws[i] = 0.f;
}

// ---------------------------------------------------------------------------
// Tiled fp32 GEMM, 128x128 tile, 8x8 per thread.
// MODE 0: enc_proj = enc_pad[48000x512] @ W_enc[512x512]         (B normal)
// MODE 1: pre_g = emb[tok][3232x512] @ W_ih[:, :512]^T + biases  (B transposed, A gathered)
// MODE 2: logits = za(+32 rows)[3232x1024] @ W_out^T + b_out     (B transposed, scattered out
//         rows, c-columns [512:1024) scaled by 1/l_all[row])
template<int MODE>
__global__ __launch_bounds__(256) void gemm_tile(
    const float* __restrict__ Abase, const float* __restrict__ Bmat,
    const float* __restrict__ bias0, const float* __restrict__ bias1,
    const int* __restrict__ ys, const float* __restrict__ l_all,
    float* __restrict__ Out, int M, int N, int K)
{
    __shared__ float As[16][132];
    __shared__ float Bs[16][132];
    const int tid = threadIdx.x;
    const int row0 = blockIdx.y * 128, n0 = blockIdx.x * 128;

    const int ar = tid >> 1, ah = tid & 1;
    int am = row0 + ar; if (am > M - 1) am = M - 1;
    const float* Arow;
    float linvA = 1.f;
    if (MODE == 0) {
        Arow = Abase + (size_t)am * 512;
    } else if (MODE == 1) {
        int t = am >> 5, b = am & 31;
        int tok = (t == 0) ? 1 : ys[b * LL + t - 1];
        Arow = Abase + (size_t)tok * 512;
    } else {
        Arow = Abase + (size_t)(am + 32) * 1024;
        linvA = 1.f / l_all[am];           // l_all laid out [t][b] == row index
    }
    const int bk = tid >> 4, bg = tid & 15;          // MODE 0
    const int bn = tid >> 1, bh = tid & 1;           // MODE 1/2
    int bnn = n0 + bn; if (bnn > N - 1) bnn = N - 1;

    const int tx = tid & 15, ty = tid >> 4;
    const int rr = ty * 8, cc = tx * 8;
    float acc[8][8] = {{0.f}};

    for (int k0 = 0; k0 < K; k0 += 16) {
        float4 a0 = *(const float4*)(Arow + k0 + ah * 8);
        float4 a1 = *(const float4*)(Arow + k0 + ah * 8 + 4);
        if (MODE == 2) {
            float sc = (k0 + ah * 8 >= 512) ? linvA : 1.f;
            a0.x *= sc; a0.y *= sc; a0.z *= sc; a0.w *= sc;
            a1.x *= sc; a1.y *= sc; a1.z *= sc; a1.w *= sc;
        }
        As[ah*8+0][ar] = a0.x; As[ah*8+1][ar] = a0.y; As[ah*8+2][ar] = a0.z; As[ah*8+3][ar] = a0.w;
        As[ah*8+4][ar] = a1.x; As[ah*8+5][ar] = a1.y; As[ah*8+6][ar] = a1.z; As[ah*8+7][ar] = a1.w;
        if (MODE == 0) {
            const float* bp = Bmat + (size_t)(k0 + bk) * N + n0 + bg * 8;
            float4 b0 = *(const float4*)(bp);
            float4 b1 = *(const float4*)(bp + 4);
            *(float4*)&Bs[bk][bg * 8]     = b0;
            *(float4*)&Bs[bk][bg * 8 + 4] = b1;
        } else {
            const float* bp = Bmat + (size_t)bnn * 1024 + k0 + bh * 8;
            float4 b0 = *(const float4*)(bp);
            float4 b1 = *(const float4*)(bp + 4);
            Bs[bh*8+0][bn] = b0.x; Bs[bh*8+1][bn] = b0.y; Bs[bh*8+2][bn] = b0.z; Bs[bh*8+3][bn] = b0.w;
            Bs[bh*8+4][bn] = b1.x; Bs[bh*8+5][bn] = b1.y; Bs[bh*8+6][bn] = b1.z; Bs[bh*8+7][bn] = b1.w;
        }
        __syncthreads();
        #pragma unroll
        for (int kk = 0; kk < 16; ++kk) {
            float4 A0 = *(const float4*)&As[kk][rr];
            float4 A1 = *(const float4*)&As[kk][rr + 4];
            float4 B0 = *(const float4*)&Bs[kk][cc];
            float4 B1 = *(const float4*)&Bs[kk][cc + 4];
            float av[8] = {A0.x, A0.y, A0.z, A0.w, A1.x, A1.y, A1.z, A1.w};
            float bv[8] = {B0.x, B0.y, B0.z, B0.w, B1.x, B1.y, B1.z, B1.w};
            #pragma unroll
            for (int i = 0; i < 8; ++i)
                #pragma unroll
                for (int j = 0; j < 8; ++j)
                    acc[i][j] += av[i] * bv[j];
        }
        __syncthreads();
    }
    #pragma unroll
    for (int i = 0; i < 8; ++i) {
        int m = row0 + rr + i;
        if (m >= M) continue;
        size_t orow;
        if (MODE == 2) { int t = m >> 5, b = m & 31; orow = ((size_t)b * SS + t) * (size_t)N; }
        else orow = (size_t)m * N;
        #pragma unroll
        for (int j = 0; j < 8; ++j) {
            int n = n0 + cc + j;
            if (n < N) {
                float v = acc[i][j];
                if (MODE == 1) v += bias0[n] + bias1[n];
                if (MODE == 2) v += bias0[n];
                Out[orow + n] = v;
            }
        }
    }
}

// ---------------------------------------------------------------------------
// Fused gates + LSTM, coalesced. One block per h in [0,512), 512 threads = 8 waves.
// Wave = (gate gl 0..3, b-half bh 0..1); lanes stride K. Weight fragments are
// wave-invariant (r = gl*512+h) -> hoisted to registers once, reused for 16 b-dots.
// Context half of za is raw (unnormalized); scaled by 1/l_all inline.
__global__ __launch_bounds__(512) void k_glstm(
    const float* __restrict__ za_t, const float* __restrict__ pre_g_t,
    const float* __restrict__ W_ih, const float* __restrict__ W_hh,
    const float* __restrict__ l_all, int t,
    float* __restrict__ c_state, float* __restrict__ za_n)
{
    __shared__ float red[128];
    const int h = blockIdx.x, tid = threadIdx.x;
    const int wave = tid >> 6, lane = tid & 63;
    const int gl = wave & 3, bh = wave >> 2;
    const int r = gl * 512 + h;
    const float* wz = W_hh + (size_t)r * 512;
    const float* wc = W_ih + (size_t)r * 1024 + 512;
    const float4 wz0 = *(const float4*)(wz + lane * 4);
    const float4 wz1 = *(const float4*)(wz + 256 + lane * 4);
    const float4 wc0 = *(const float4*)(wc + lane * 4);
    const float4 wc1 = *(const float4*)(wc + 256 + lane * 4);

    #pragma unroll 2
    for (int i = 0; i < 16; ++i) {
        const int b = bh * 16 + i;
        const float* zr = za_t + b * KCZ;
        float4 z0 = *(const float4*)(zr + lane * 4);
        float4 z1 = *(const float4*)(zr + 256 + lane * 4);
        float4 c0 = *(const float4*)(zr + 512 + lane * 4);
        float4 c1 = *(const float4*)(zr + 768 + lane * 4);
        float az = z0.x*wz0.x + z0.y*wz0.y + z0.z*wz0.z + z0.w*wz0.w
                 + z1.x*wz1.x + z1.y*wz1.y + z1.z*wz1.z + z1.w*wz1.w;
        float ac = c0.x*wc0.x + c0.y*wc0.y + c0.z*wc0.z + c0.w*wc0.w
                 + c1.x*wc1.x + c1.y*wc1.y + c1.z*wc1.z + c1.w*wc1.w;
        float linv = (t == 0) ? 0.f : 1.f / l_all[(t - 1) * 32 + b];
        float v = az + ac * linv;
        #pragma unroll
        for (int off = 32; off > 0; off >>= 1) v += __shfl_xor(v, off);
        if (lane == 0) red[gl * 32 + b] = v;
    }
    __syncthreads();
    if (tid < 32) {
        const int bb = tid;
        const float* pg = pre_g_t + bb * G4 + h;
        float vi = red[  0 + bb] + pg[0];
        float vf = red[ 32 + bb] + pg[512];
        float vg = red[ 64 + bb] + pg[1024];
        float vo = red[ 96 + bb] + pg[1536];
        float ig = sigm(vi), fg = sigm(vf), gg = tanhf(vg), og = sigm(vo);
        float c = fg * c_state[bb * 512 + h] + ig * gg;
        c_state[bb * 512 + h] = c;
        za_n[bb * KCZ + h] = og * tanhf(c);
    }
}

// ---------------------------------------------------------------------------
// q = z_new @ W_dec, split-K. grid (16 jc, 32 b); thread = (j-lane 0..31, kseg 0..7)
__global__ __launch_bounds__(256) void k_qproj(const float* __restrict__ za_n,
                                               const float* __restrict__ W_dec,
                                               float* __restrict__ q)
{
    __shared__ float red[256];
    const int tid = threadIdx.x;
    const int j = blockIdx.x * 32 + (tid & 31);
    const int b = blockIdx.y;
    const int k0 = (tid >> 5) * 64;
    const float* z = za_n + b * KCZ + k0;
    const float* wd = W_dec + (size_t)k0 * 512 + j;
    float acc = 0.f;
    #pragma unroll 8
    for (int k = 0; k < 64; k += 4) {
        float4 z4 = *(const float4*)(z + k);
        acc += z4.x * wd[(k + 0) * 512] + z4.y * wd[(k + 1) * 512]
             + z4.z * wd[(k + 2) * 512] + z4.w * wd[(k + 3) * 512];
    }
    red[tid] = acc;
    __syncthreads();
    if (tid < 32) {
        float s = red[tid] + red[tid + 32] + red[tid + 64] + red[tid + 96]
                + red[tid + 128] + red[tid + 160] + red[tid + 192] + red[tid + 224];
        q[b * 512 + blockIdx.x * 32 + tid] = s;
    }
}

// ---------------------------------------------------------------------------
// Fused attention: e -> p=exp(e-10) -> raw p to ws row, unnormalized context
// accumulated into za_next c-half, l into l_all[t][b].
// grid (47 t-chunks, 32 b), 256 threads = 4 waves; wave handles one t' at a time.
__global__ __launch_bounds__(256) void k_att(
    const float* __restrict__ enc_proj, const float* __restrict__ enc_pad,
    const float* __restrict__ q, const float* __restrict__ v_att,
    const int* __restrict__ enc_len,
    float* __restrict__ za_n, float* __restrict__ l_t, float* __restrict__ w_raw)
{
    __shared__ float q_s[512], v_s[512];
    __shared__ float accs[4][512];
    __shared__ float lsum_s[4];
    const int b = blockIdx.y, tc = blockIdx.x, tid = threadIdx.x;
    int len = enc_len[b]; if (len > TENC) len = TENC;
    const int base = tc * ACH;
    int tlim = base + ACH;
    if (tlim > len) tlim = len;
    if (base >= tlim) return;                 // block-uniform, before any sync

    for (int i = tid; i < 512; i += 256) { q_s[i] = q[b * 512 + i]; v_s[i] = v_att[i]; }
    __syncthreads();
    const int wave = tid >> 6, lane = tid & 63;
    float a[8] = {0.f, 0.f, 0.f, 0.f, 0.f, 0.f, 0.f, 0.f};
    float lacc = 0.f;
    float qv[8], vv8[8];
    #pragma unroll
    for (int j = 0; j < 8; ++j) { qv[j] = q_s[lane * 8 + j]; vv8[j] = v_s[lane * 8 + j]; }

    for (int tp = base + wave; tp < tlim; tp += 4) {
        const float* ep = enc_proj + ((size_t)b * TENC + tp) * 512 + lane * 8;
        float4 e0 = *(const float4*)(ep);
        float4 e1 = *(const float4*)(ep + 4);
        float s = tanh_fast(e0.x + qv[0]) * vv8[0] + tanh_fast(e0.y + qv[1]) * vv8[1]
                + tanh_fast(e0.z + qv[2]) * vv8[2] + tanh_fast(e0.w + qv[3]) * vv8[3]
                + tanh_fast(e1.x + qv[4]) * vv8[4] + tanh_fast(e1.y + qv[5]) * vv8[5]
                + tanh_fast(e1.z + qv[6]) * vv8[6] + tanh_fast(e1.w + qv[7]) * vv8[7];
        #pragma unroll
        for (int off = 32; off > 0; off >>= 1) s += __shfl_xor(s, off);
        float p = __expf(s - 10.f);
        if (lane == 0) w_raw[(size_t)b * (SS * TENC) + tp] = p;
        lacc += p;
        const float* xp = enc_pad + ((size_t)b * TENC + tp) * 512 + lane * 8;
        float4 x0 = *(const float4*)(xp);
        float4 x1 = *(const float4*)(xp + 4);
        a[0] += p * x0.x; a[1] += p * x0.y; a[2] += p * x0.z; a[3] += p * x0.w;
        a[4] += p * x1.x; a[5] += p * x1.y; a[6] += p * x1.z; a[7] += p * x1.w;
    }
    #pragma unroll
    for (int j = 0; j < 8; ++j) accs[wave][lane * 8 + j] = a[j];
    if (lane == 0) lsum_s[wave] = lacc;
    __syncthreads();
    for (int d = tid; d < 512; d += 256) {
        float s = accs[0][d] + accs[1][d] + accs[2][d] + accs[3][d];
        atomicAdd(&za_n[b * KCZ + 512 + d], s);
    }
    if (tid == 0) atomicAdd(&l_t[b], lsum_s[0] + lsum_s[1] + lsum_s[2] + lsum_s[3]);
}

// ---------------------------------------------------------------------------
// Normalize all attention-weight rows in one pass. grid 3232 = B*SS rows.
__global__ __launch_bounds__(256) void k_wnorm(float* __restrict__ wsatt,
                                               const float* __restrict__ l_all,
                                               const int* __restrict__ enc_len)
{
    const int rid = blockIdx.x;               // b*SS + t
    const int b = rid / SS, t = rid % SS;
    const float linv = 1.f / l_all[t * 32 + b];
    const int len = enc_len[b];
    float* row = wsatt + (size_t)rid * TENC;
    for (int tp = threadIdx.x; tp < TENC; tp += 256)
        row[tp] = (tp < len) ? row[tp] * linv : 0.f;
}

// ---------------------------------------------------------------------------
// Per-row log-softmax stats: max, argmax(first), logsumexp -> ys_lp, pred
__global__ __launch_bounds__(256) void k_logsm(const float* __restrict__ logits,
                                               const int* __restrict__ ys,
                                               float* __restrict__ ys_lp,
                                               float* __restrict__ pred)
{
    __shared__ float sval[256];
    __shared__ int   sidx[256];
    __shared__ float ssum[256];
    const int bid = blockIdx.x, tid = threadIdx.x;
    const float* row = logits + (size_t)bid * VV;
    float vmax = -3.4e38f; int imax = 0;
    for (int v4 = tid; v4 < VV / 4; v4 += 256) {
        float4 x = *(const float4*)(row + v4 * 4);
        int basei = v4 * 4;
        if (x.x > vmax) { vmax = x.x; imax = basei; }
        if (x.y > vmax) { vmax = x.y; imax = basei + 1; }
        if (x.z > vmax) { vmax = x.z; imax = basei + 2; }
        if (x.w > vmax) { vmax = x.w; imax = basei + 3; }
    }
    sval[tid] = vmax; sidx[tid] = imax;
    __syncthreads();
    for (int s = 128; s > 0; s >>= 1) {
        if (tid < s) {
            float v2 = sval[tid + s]; int i2 = sidx[tid + s];
            if (v2 > sval[tid] || (v2 == sval[tid] && i2 < sidx[tid])) { sval[tid] = v2; sidx[tid] = i2; }
        }
        __syncthreads();
    }
    const float gmax = sval[0];
    float lsum = 0.f;
    for (int v4 = tid; v4 < VV / 4; v4 += 256) {
        float4 x = *(const float4*)(row + v4 * 4);
        lsum += __expf(x.x - gmax) + __expf(x.y - gmax) + __expf(x.z - gmax) + __expf(x.w - gmax);
    }
    ssum[tid] = lsum;
    __syncthreads();
    for (int s = 128; s > 0; s >>= 1) {
        if (tid < s) ssum[tid] += ssum[tid + s];
        __syncthreads();
    }
    if (tid == 0) {
        int b = bid / SS, t = bid % SS;
        int tok = (t < LL) ? ys[b * LL + t] : 2;   // EOS = 2
        ys_lp[bid] = row[tok] - gmax - logf(ssum[0]);
        pred[bid]  = (float)sidx[0];
    }
}

// ---------------------------------------------------------------------------
extern "C" void kernel_launch(void* const* d_in, const int* in_sizes, int n_in,
                              void* d_out, int out_size, void* d_ws, size_t ws_size,
                              hipStream_t stream)
{
    const float* enc_pad = (const float*)d_in[0];
    const int*   enc_len = (const int*)d_in[1];
    const int*   ys      = (const int*)d_in[2];
    const float* emb     = (const float*)d_in[3];
    const float* W_ih    = (const float*)d_in[4];
    const float* W_hh    = (const float*)d_in[5];
    const float* b_ih    = (const float*)d_in[6];
    const float* b_hh    = (const float*)d_in[7];
    const float* W_enc   = (const float*)d_in[8];
    const float* W_dec   = (const float*)d_in[9];
    const float* v_att   = (const float*)d_in[10];
    const float* W_out   = (const float*)d_in[11];
    const float* b_out   = (const float*)d_in[12];

    float* out = (float*)d_out;
    float* enc_proj = out + OUT_ENCP;
    float* pre_g    = out + OUT_PREG;
    float* logits   = out + OUT_LOGITS;
    float* ys_lp    = out + OUT_YSLP;
    float* predo    = out + OUT_PRED;
    float* wsatt    = out + OUT_WS;

    float* ws = (float*)d_ws;
    float* za      = ws + WS_ZA;            // 102*32*1024
    float* c_state = ws + WS_CST;           // 32*512
    float* l_all   = ws + WS_LALL;          // 101*32
    float* qbuf    = ws + WS_Q;             // 32*512

    // Prologue
    zero_kernel<<<(WS_ZERON + 255) / 256, 256, 0, stream>>>(ws);
    gemm_tile<0><<<dim3(4, 375), 256, 0, stream>>>(enc_pad, W_enc, nullptr, nullptr, nullptr,
                                                   nullptr, enc_proj, BZ * TENC, 512, 512);
    gemm_tile<1><<<dim3(16, 26), 256, 0, stream>>>(emb, W_ih, b_ih, b_hh, ys,
                                                   nullptr, pre_g, BZ * SS, G4, 512);

    // Sequential decode: 3 kernels per step
    for (int t = 0; t < SS; ++t) {
        float* za_t    = za + (size_t)t * (BZ * KCZ);
        float* za_next = za_t + BZ * KCZ;
        k_glstm<<<512, 512, 0, stream>>>(za_t, pre_g + (size_t)t * (BZ * G4),
                                         W_ih, W_hh, l_all, t, c_state, za_next);
        k_qproj<<<dim3(16, 32), 256, 0, stream>>>(za_next, W_dec, qbuf);
        k_att<<<dim3(NCH, 32), 256, 0, stream>>>(enc_proj, enc_pad, qbuf, v_att, enc_len,
                                                 za_next, l_all + t * 32,
                                                 wsatt + (size_t)t * TENC);
    }

    // Epilogue
    k_wnorm<<<BZ * SS, 256, 0, stream>>>(wsatt, l_all, enc_len);
    gemm_tile<2><<<dim3(79, 26), 256, 0, stream>>>(za, W_out, b_out, nullptr, nullptr,
                                                   l_all, logits, BZ * SS, VV, 1024);
    k_logsm<<<BZ * SS, 256, 0, stream>>>(logits, ys, ys_lp, predo);
}

// Round 5
// 5814.665 us; speedup vs baseline: 5.6018x; 1.0767x over previous
//
#include <hip/hip_runtime.h>
#include <math.h>

// Problem constants
#define BZ   32
#define TENC 1500
#define DD   512      // E == H == A == ATT_H == 512
#define VV   10000
#define LL   100
#define SS   101      // L+1 steps
#define G4   2048     // 4*H
#define KCZ  1024     // H + A
#define ACH  32       // attention t-chunk size
#define NCH  47       // ceil(1500/32)

// d_out float offsets
#define OUT_LOGITS 0
#define OUT_ENCPBF 0                      // bf16 enc_proj overlay: 24.576M ushort = 12.288M floats
#define OUT_PREG   24576000               // 32*101*2048 = 6.62M floats (ends 31.2M < 32.32M)
#define OUT_YSLP   32320000               // logits end here (32*101*10000)
#define OUT_PRED   32323232
#define OUT_WS     32326464

// ws float offsets
#define WS_ZA      0                      // 102*32*1024 = 3342336
#define WS_CST     3342336                // 32*512 = 16384
#define WS_LALL    3358720                // 101*32 = 3232
#define WS_Q       3361952                // 32*512
#define WS_ZERON   3361952                // floats zeroed at prologue (za + c_state + l_all)

__device__ inline float sigm(float x) { return 1.f / (1.f + __expf(-x)); }
__device__ inline float tanh_fast(float x) {
    x = fminf(15.f, fmaxf(-15.f, x));
    float e = __expf(2.f * x);
    return (e - 1.f) / (e + 1.f);
}
// fp32 -> bf16 (round-to-nearest-even), and bf16-pair unpack helpers
__device__ inline unsigned short f2bf(float x) {
    unsigned int u = __float_as_uint(x);
    u = (u + 0x7FFFu + ((u >> 16) & 1u)) >> 16;
    return (unsigned short)u;
}
__device__ inline float bf_lo(unsigned int u) { return __uint_as_float(u << 16); }
__device__ inline float bf_hi(unsigned int u) { return __uint_as_float(u & 0xFFFF0000u); }

// ---------------------------------------------------------------------------
// Zero init: za (all slots) + c_state + l_all, contiguous in ws
__global__ void zero_kernel(float* ws) {
    size_t i = (size_t)blockIdx.x * 256 + threadIdx.x;
    if (i < WS_ZERON) ws[i] = 0.f;
}

// ---------------------------------------------------------------------------
// Tiled fp32 GEMM, 128x128 tile, 8x8 per thread.
// MODE 0: enc_proj = enc_pad[48000x512] @ W_enc[512x512]  -> bf16 packed output (scores only)
// MODE 1: pre_g = emb[tok][3232x512] @ W_ih[:, :512]^T + biases  (B transposed, A gathered)
// MODE 2: logits = za(+32 rows)[3232x1024] @ W_out^T + b_out     (B transposed, scattered out
//         rows, c-columns [512:1024) scaled by 1/l_all[row])
template<int MODE>
__global__ __launch_bounds__(256) void gemm_tile(
    const float* __restrict__ Abase, const float* __restrict__ Bmat,
    const float* __restrict__ bias0, const float* __restrict__ bias1,
    const int* __restrict__ ys, const float* __restrict__ l_all,
    float* __restrict__ Out, int M, int N, int K)
{
    __shared__ float As[16][132];
    __shared__ float Bs[16][132];
    const int tid = threadIdx.x;
    const int row0 = blockIdx.y * 128, n0 = blockIdx.x * 128;

    const int ar = tid >> 1, ah = tid & 1;
    int am = row0 + ar; if (am > M - 1) am = M - 1;
    const float* Arow;
    float linvA = 1.f;
    if (MODE == 0) {
        Arow = Abase + (size_t)am * 512;
    } else if (MODE == 1) {
        int t = am >> 5, b = am & 31;
        int tok = (t == 0) ? 1 : ys[b * LL + t - 1];
        Arow = Abase + (size_t)tok * 512;
    } else {
        Arow = Abase + (size_t)(am + 32) * 1024;
        linvA = 1.f / l_all[am];           // l_all laid out [t][b] == row index
    }
    const int bk = tid >> 4, bg = tid & 15;          // MODE 0
    const int bn = tid >> 1, bh = tid & 1;           // MODE 1/2
    int bnn = n0 + bn; if (bnn > N - 1) bnn = N - 1;

    const int tx = tid & 15, ty = tid >> 4;
    const int rr = ty * 8, cc = tx * 8;
    float acc[8][8] = {{0.f}};

    for (int k0 = 0; k0 < K; k0 += 16) {
        float4 a0 = *(const float4*)(Arow + k0 + ah * 8);
        float4 a1 = *(const float4*)(Arow + k0 + ah * 8 + 4);
        if (MODE == 2) {
            float sc = (k0 + ah * 8 >= 512) ? linvA : 1.f;
            a0.x *= sc; a0.y *= sc; a0.z *= sc; a0.w *= sc;
            a1.x *= sc; a1.y *= sc; a1.z *= sc; a1.w *= sc;
        }
        As[ah*8+0][ar] = a0.x; As[ah*8+1][ar] = a0.y; As[ah*8+2][ar] = a0.z; As[ah*8+3][ar] = a0.w;
        As[ah*8+4][ar] = a1.x; As[ah*8+5][ar] = a1.y; As[ah*8+6][ar] = a1.z; As[ah*8+7][ar] = a1.w;
        if (MODE == 0) {
            const float* bp = Bmat + (size_t)(k0 + bk) * N + n0 + bg * 8;
            float4 b0 = *(const float4*)(bp);
            float4 b1 = *(const float4*)(bp + 4);
            *(float4*)&Bs[bk][bg * 8]     = b0;
            *(float4*)&Bs[bk][bg * 8 + 4] = b1;
        } else {
            const float* bp = Bmat + (size_t)bnn * 1024 + k0 + bh * 8;
            float4 b0 = *(const float4*)(bp);
            float4 b1 = *(const float4*)(bp + 4);
            Bs[bh*8+0][bn] = b0.x; Bs[bh*8+1][bn] = b0.y; Bs[bh*8+2][bn] = b0.z; Bs[bh*8+3][bn] = b0.w;
            Bs[bh*8+4][bn] = b1.x; Bs[bh*8+5][bn] = b1.y; Bs[bh*8+6][bn] = b1.z; Bs[bh*8+7][bn] = b1.w;
        }
        __syncthreads();
        #pragma unroll
        for (int kk = 0; kk < 16; ++kk) {
            float4 A0 = *(const float4*)&As[kk][rr];
            float4 A1 = *(const float4*)&As[kk][rr + 4];
            float4 B0 = *(const float4*)&Bs[kk][cc];
            float4 B1 = *(const float4*)&Bs[kk][cc + 4];
            float av[8] = {A0.x, A0.y, A0.z, A0.w, A1.x, A1.y, A1.z, A1.w};
            float bv[8] = {B0.x, B0.y, B0.z, B0.w, B1.x, B1.y, B1.z, B1.w};
            #pragma unroll
            for (int i = 0; i < 8; ++i)
                #pragma unroll
                for (int j = 0; j < 8; ++j)
                    acc[i][j] += av[i] * bv[j];
        }
        __syncthreads();
    }
    if (MODE == 0) {
        // bf16 packed output; M=48000, N=512 exact multiples -> no bounds checks
        unsigned short* ob = (unsigned short*)Out;
        #pragma unroll
        for (int i = 0; i < 8; ++i) {
            int m = row0 + rr + i;
            uint4 o;
            o.x = (unsigned int)f2bf(acc[i][0]) | ((unsigned int)f2bf(acc[i][1]) << 16);
            o.y = (unsigned int)f2bf(acc[i][2]) | ((unsigned int)f2bf(acc[i][3]) << 16);
            o.z = (unsigned int)f2bf(acc[i][4]) | ((unsigned int)f2bf(acc[i][5]) << 16);
            o.w = (unsigned int)f2bf(acc[i][6]) | ((unsigned int)f2bf(acc[i][7]) << 16);
            *(uint4*)(ob + (size_t)m * 512 + n0 + cc) = o;
        }
    } else {
        #pragma unroll
        for (int i = 0; i < 8; ++i) {
            int m = row0 + rr + i;
            if (m >= M) continue;
            size_t orow;
            if (MODE == 2) { int t = m >> 5, b = m & 31; orow = ((size_t)b * SS + t) * (size_t)N; }
            else orow = (size_t)m * N;
            #pragma unroll
            for (int j = 0; j < 8; ++j) {
                int n = n0 + cc + j;
                if (n < N) {
                    float v = acc[i][j];
                    if (MODE == 1) v += bias0[n] + bias1[n];
                    if (MODE == 2) v += bias0[n];
                    Out[orow + n] = v;
                }
            }
        }
    }
}

// ---------------------------------------------------------------------------
// Fused gates + LSTM, coalesced, no za re-read. One block per h, 512 threads = 8 waves.
// Wave = b-group of 4; each wave holds ALL 4 gates' weight fragments in registers
// (r = g*512+h wave-invariant) and reads each za row exactly once.
// (Numerically identical to the R3 version: same per-(g,b,h) partial sets, same shfl tree.)
__global__ __launch_bounds__(512) void k_glstm(
    const float* __restrict__ za_t, const float* __restrict__ pre_g_t,
    const float* __restrict__ W_ih, const float* __restrict__ W_hh,
    const float* __restrict__ l_all, int t,
    float* __restrict__ c_state, float* __restrict__ za_n)
{
    __shared__ float red[128];                 // [gate][b]
    const int h = blockIdx.x, tid = threadIdx.x;
    const int wave = tid >> 6, lane = tid & 63;
    float4 wz0[4], wz1[4], wc0[4], wc1[4];
    #pragma unroll
    for (int g = 0; g < 4; ++g) {
        const float* wz = W_hh + (size_t)(g * 512 + h) * 512;
        const float* wc = W_ih + (size_t)(g * 512 + h) * 1024 + 512;
        wz0[g] = *(const float4*)(wz + lane * 4);
        wz1[g] = *(const float4*)(wz + 256 + lane * 4);
        wc0[g] = *(const float4*)(wc + lane * 4);
        wc1[g] = *(const float4*)(wc + 256 + lane * 4);
    }
    #pragma unroll
    for (int i = 0; i < 4; ++i) {
        const int b = wave * 4 + i;
        const float* zr = za_t + b * KCZ;
        float4 z0 = *(const float4*)(zr + lane * 4);
        float4 z1 = *(const float4*)(zr + 256 + lane * 4);
        float4 c0 = *(const float4*)(zr + 512 + lane * 4);
        float4 c1 = *(const float4*)(zr + 768 + lane * 4);
        float linv = (t == 0) ? 0.f : 1.f / l_all[(t - 1) * 32 + b];
        #pragma unroll
        for (int g = 0; g < 4; ++g) {
            float az = z0.x*wz0[g].x + z0.y*wz0[g].y + z0.z*wz0[g].z + z0.w*wz0[g].w
                     + z1.x*wz1[g].x + z1.y*wz1[g].y + z1.z*wz1[g].z + z1.w*wz1[g].w;
            float ac = c0.x*wc0[g].x + c0.y*wc0[g].y + c0.z*wc0[g].z + c0.w*wc0[g].w
                     + c1.x*wc1[g].x + c1.y*wc1[g].y + c1.z*wc1[g].z + c1.w*wc1[g].w;
            float v = az + ac * linv;
            #pragma unroll
            for (int off = 32; off > 0; off >>= 1) v += __shfl_xor(v, off);
            if (lane == 0) red[g * 32 + b] = v;
        }
    }
    __syncthreads();
    if (tid < 32) {
        const int bb = tid;
        const float* pg = pre_g_t + bb * G4 + h;
        float vi = red[  0 + bb] + pg[0];
        float vf = red[ 32 + bb] + pg[512];
        float vg = red[ 64 + bb] + pg[1024];
        float vo = red[ 96 + bb] + pg[1536];
        float ig = sigm(vi), fg = sigm(vf), gg = tanhf(vg), og = sigm(vo);
        float c = fg * c_state[bb * 512 + h] + ig * gg;
        c_state[bb * 512 + h] = c;
        za_n[bb * KCZ + h] = og * tanhf(c);
    }
}

// ---------------------------------------------------------------------------
// q = z_new @ W_dec, split-K. grid (16 jc, 32 b); thread = (j-lane 0..31, kseg 0..7)
__global__ __launch_bounds__(256) void k_qproj(const float* __restrict__ za_n,
                                               const float* __restrict__ W_dec,
                                               float* __restrict__ q)
{
    __shared__ float red[256];
    const int tid = threadIdx.x;
    const int j = blockIdx.x * 32 + (tid & 31);
    const int b = blockIdx.y;
    const int k0 = (tid >> 5) * 64;
    const float* z = za_n + b * KCZ + k0;
    const float* wd = W_dec + (size_t)k0 * 512 + j;
    float acc = 0.f;
    #pragma unroll 8
    for (int k = 0; k < 64; k += 4) {
        float4 z4 = *(const float4*)(z + k);
        acc += z4.x * wd[(k + 0) * 512] + z4.y * wd[(k + 1) * 512]
             + z4.z * wd[(k + 2) * 512] + z4.w * wd[(k + 3) * 512];
    }
    red[tid] = acc;
    __syncthreads();
    if (tid < 32) {
        float s = red[tid] + red[tid + 32] + red[tid + 64] + red[tid + 96]
                + red[tid + 128] + red[tid + 160] + red[tid + 192] + red[tid + 224];
        q[b * 512 + blockIdx.x * 32 + tid] = s;
    }
}

// ---------------------------------------------------------------------------
// Fused attention: scores from bf16 enc_proj, context from fp32 enc_pad.
// e -> p=exp(e-10) -> raw p to ws row, unnormalized context accumulated into
// za_next c-half, l into l_all[t][b].
// grid (47 t-chunks, 32 b), 256 threads = 4 waves; wave handles one t' at a time.
__global__ __launch_bounds__(256) void k_att(
    const unsigned short* __restrict__ encp_bf, const float* __restrict__ enc_pad,
    const float* __restrict__ q, const float* __restrict__ v_att,
    const int* __restrict__ enc_len,
    float* __restrict__ za_n, float* __restrict__ l_t, float* __restrict__ w_raw)
{
    __shared__ float q_s[512], v_s[512];
    __shared__ float accs[4][512];
    __shared__ float lsum_s[4];
    const int b = blockIdx.y, tc = blockIdx.x, tid = threadIdx.x;
    int len = enc_len[b]; if (len > TENC) len = TENC;
    const int base = tc * ACH;
    int tlim = base + ACH;
    if (tlim > len) tlim = len;
    if (base >= tlim) return;                 // block-uniform, before any sync

    for (int i = tid; i < 512; i += 256) { q_s[i] = q[b * 512 + i]; v_s[i] = v_att[i]; }
    __syncthreads();
    const int wave = tid >> 6, lane = tid & 63;
    float a[8] = {0.f, 0.f, 0.f, 0.f, 0.f, 0.f, 0.f, 0.f};
    float lacc = 0.f;
    float qv[8], vv8[8];
    #pragma unroll
    for (int j = 0; j < 8; ++j) { qv[j] = q_s[lane * 8 + j]; vv8[j] = v_s[lane * 8 + j]; }

    for (int tp = base + wave; tp < tlim; tp += 4) {
        const size_t roff = ((size_t)b * TENC + tp) * 512 + lane * 8;
        uint4 E = *(const uint4*)(encp_bf + roff);
        float s = tanh_fast(bf_lo(E.x) + qv[0]) * vv8[0] + tanh_fast(bf_hi(E.x) + qv[1]) * vv8[1]
                + tanh_fast(bf_lo(E.y) + qv[2]) * vv8[2] + tanh_fast(bf_hi(E.y) + qv[3]) * vv8[3]
                + tanh_fast(bf_lo(E.z) + qv[4]) * vv8[4] + tanh_fast(bf_hi(E.z) + qv[5]) * vv8[5]
                + tanh_fast(bf_lo(E.w) + qv[6]) * vv8[6] + tanh_fast(bf_hi(E.w) + qv[7]) * vv8[7];
        #pragma unroll
        for (int off = 32; off > 0; off >>= 1) s += __shfl_xor(s, off);
        float p = __expf(s - 10.f);
        if (lane == 0) w_raw[(size_t)b * (SS * TENC) + tp] = p;
        lacc += p;
        const float* xp = enc_pad + roff;
        float4 x0 = *(const float4*)(xp);
        float4 x1 = *(const float4*)(xp + 4);
        a[0] += p * x0.x; a[1] += p * x0.y; a[2] += p * x0.z; a[3] += p * x0.w;
        a[4] += p * x1.x; a[5] += p * x1.y; a[6] += p * x1.z; a[7] += p * x1.w;
    }
    #pragma unroll
    for (int j = 0; j < 8; ++j) accs[wave][lane * 8 + j] = a[j];
    if (lane == 0) lsum_s[wave] = lacc;
    __syncthreads();
    for (int d = tid; d < 512; d += 256) {
        float s = accs[0][d] + accs[1][d] + accs[2][d] + accs[3][d];
        atomicAdd(&za_n[b * KCZ + 512 + d], s);
    }
    if (tid == 0) atomicAdd(&l_t[b], lsum_s[0] + lsum_s[1] + lsum_s[2] + lsum_s[3]);
}

// ---------------------------------------------------------------------------
// Normalize all attention-weight rows in one pass. grid 3232 = B*SS rows.
__global__ __launch_bounds__(256) void k_wnorm(float* __restrict__ wsatt,
                                               const float* __restrict__ l_all,
                                               const int* __restrict__ enc_len)
{
    const int rid = blockIdx.x;               // b*SS + t
    const int b = rid / SS, t = rid % SS;
    const float linv = 1.f / l_all[t * 32 + b];
    const int len = enc_len[b];
    float* row = wsatt + (size_t)rid * TENC;
    for (int tp = threadIdx.x; tp < TENC; tp += 256)
        row[tp] = (tp < len) ? row[tp] * linv : 0.f;
}

// ---------------------------------------------------------------------------
// Per-row log-softmax stats, SINGLE PASS online: max, argmax(first), logsumexp.
// Argmax semantics preserved: per-thread strict-greater chain keeps first index;
// block reduce prefers lower index on ties.
__global__ __launch_bounds__(256) void k_logsm(const float* __restrict__ logits,
                                               const int* __restrict__ ys,
                                               float* __restrict__ ys_lp,
                                               float* __restrict__ pred)
{
    __shared__ float sval[256];
    __shared__ int   sidx[256];
    __shared__ float ssum[256];
    const int bid = blockIdx.x, tid = threadIdx.x;
    const float* row = logits + (size_t)bid * VV;
    float vmax = -3.4e38f; int imax = 0; float lsum = 0.f;
    for (int v4 = tid; v4 < VV / 4; v4 += 256) {
        float4 x = *(const float4*)(row + v4 * 4);
        int basei = v4 * 4;
        float e[4] = {x.x, x.y, x.z, x.w};
        #pragma unroll
        for (int j = 0; j < 4; ++j) {
            float v = e[j];
            if (v > vmax) {
                lsum = lsum * __expf(vmax - v) + 1.f;
                vmax = v; imax = basei + j;
            } else {
                lsum += __expf(v - vmax);
            }
        }
    }
    sval[tid] = vmax; sidx[tid] = imax; ssum[tid] = lsum;
    __syncthreads();
    for (int s = 128; s > 0; s >>= 1) {
        if (tid < s) {
            float v2 = sval[tid + s]; int i2 = sidx[tid + s]; float s2 = ssum[tid + s];
            float v1 = sval[tid];
            if (v2 > v1 || (v2 == v1 && i2 < sidx[tid])) {
                ssum[tid] = s2 + ssum[tid] * __expf(v1 - v2);
                sval[tid] = v2; sidx[tid] = i2;
            } else {
                ssum[tid] = ssum[tid] + s2 * __expf(v2 - v1);
            }
        }
        __syncthreads();
    }
    if (tid == 0) {
        int b = bid / SS, t = bid % SS;
        int tok = (t < LL) ? ys[b * LL + t] : 2;   // EOS = 2
        ys_lp[bid] = row[tok] - sval[0] - logf(ssum[0]);
        pred[bid]  = (float)sidx[0];
    }
}

// ---------------------------------------------------------------------------
extern "C" void kernel_launch(void* const* d_in, const int* in_sizes, int n_in,
                              void* d_out, int out_size, void* d_ws, size_t ws_size,
                              hipStream_t stream)
{
    const float* enc_pad = (const float*)d_in[0];
    const int*   enc_len = (const int*)d_in[1];
    const int*   ys      = (const int*)d_in[2];
    const float* emb     = (const float*)d_in[3];
    const float* W_ih    = (const float*)d_in[4];
    const float* W_hh    = (const float*)d_in[5];
    const float* b_ih    = (const float*)d_in[6];
    const float* b_hh    = (const float*)d_in[7];
    const float* W_enc   = (const float*)d_in[8];
    const float* W_dec   = (const float*)d_in[9];
    const float* v_att   = (const float*)d_in[10];
    const float* W_out   = (const float*)d_in[11];
    const float* b_out   = (const float*)d_in[12];

    float* out = (float*)d_out;
    unsigned short* encp_bf = (unsigned short*)(out + OUT_ENCPBF);
    float* pre_g    = out + OUT_PREG;
    float* logits   = out + OUT_LOGITS;
    float* ys_lp    = out + OUT_YSLP;
    float* predo    = out + OUT_PRED;
    float* wsatt    = out + OUT_WS;

    float* ws = (float*)d_ws;
    float* za      = ws + WS_ZA;            // 102*32*1024
    float* c_state = ws + WS_CST;           // 32*512
    float* l_all   = ws + WS_LALL;          // 101*32
    float* qbuf    = ws + WS_Q;             // 32*512

    // Prologue
    zero_kernel<<<(WS_ZERON + 255) / 256, 256, 0, stream>>>(ws);
    gemm_tile<0><<<dim3(4, 375), 256, 0, stream>>>(enc_pad, W_enc, nullptr, nullptr, nullptr,
                                                   nullptr, (float*)encp_bf, BZ * TENC, 512, 512);
    gemm_tile<1><<<dim3(16, 26), 256, 0, stream>>>(emb, W_ih, b_ih, b_hh, ys,
                                                   nullptr, pre_g, BZ * SS, G4, 512);

    // Sequential decode: 3 kernels per step
    for (int t = 0; t < SS; ++t) {
        float* za_t    = za + (size_t)t * (BZ * KCZ);
        float* za_next = za_t + BZ * KCZ;
        k_glstm<<<512, 512, 0, stream>>>(za_t, pre_g + (size_t)t * (BZ * G4),
                                         W_ih, W_hh, l_all, t, c_state, za_next);
        k_qproj<<<dim3(16, 32), 256, 0, stream>>>(za_next, W_dec, qbuf);
        k_att<<<dim3(NCH, 32), 256, 0, stream>>>(encp_bf, enc_pad, qbuf, v_att, enc_len,
                                                 za_next, l_all + t * 32,
                                                 wsatt + (size_t)t * TENC);
    }

    // Epilogue
    k_wnorm<<<BZ * SS, 256, 0, stream>>>(wsatt, l_all, enc_len);
    gemm_tile<2><<<dim3(79, 26), 256, 0, stream>>>(za, W_out, b_out, nullptr, nullptr,
                                                   l_all, logits, BZ * SS, VV, 1024);
    k_logsm<<<BZ * SS, 256, 0, stream>>>(logits, ys, ys_lp, predo);
}